// Round 20
// baseline (298.290 us; speedup 1.0000x reference)
//
#include <hip/hip_runtime.h>
#include <math.h>

#define NROWS 500000
#define DIM 256
#define YDIM 50
#define NLAB 1000

#define XT 32
#define NTX (NROWS / XT)                 // 15625 exact
#define XBLK 512                         // 2 blocks/CU
#define ASTRIDE 264
#define ZSTR 32                          // u32 (bf16-pair) per z row = 128 B

typedef __attribute__((ext_vector_type(8))) short frag_ab;
typedef __attribute__((ext_vector_type(4))) float frag_cd;

__device__ __forceinline__ float b2f(unsigned short u) {
    return __uint_as_float(((unsigned)u) << 16);
}
__device__ __forceinline__ unsigned short f2b(float f) {
    unsigned u = __float_as_uint(f);
    return (unsigned short)((u + 0x7fffu + ((u >> 16) & 1u)) >> 16);
}
__device__ __forceinline__ unsigned cvt_pk_bf16(float lo, float hi) {
    unsigned r;
    asm("v_cvt_pk_bf16_f32 %0, %1, %2" : "=v"(r) : "v"(lo), "v"(hi));
    return r;
}
__device__ __forceinline__ void bar_lds() {
    asm volatile("s_waitcnt lgkmcnt(0)\n\ts_barrier" ::: "memory");
}

// ---------- R2-verified: label histogram ----------
__global__ __launch_bounds__(256) void k_hist(const int* __restrict__ labels,
                                              int* __restrict__ hist) {
    __shared__ int lh[NLAB];
    for (int i = threadIdx.x; i < NLAB; i += 256) lh[i] = 0;
    __syncthreads();
    for (int i = blockIdx.x * 256 + threadIdx.x; i < NROWS; i += gridDim.x * 256)
        atomicAdd(&lh[labels[i]], 1);
    __syncthreads();
    for (int i = threadIdx.x; i < NLAB; i += 256) {
        int v = lh[i];
        if (v) atomicAdd(&hist[i], v);
    }
}

// ---------- R2-verified: exclusive scan over 1000 bins (+ zero out) ----------
__global__ __launch_bounds__(1024) void k_scan(const int* __restrict__ hist,
                                               int* __restrict__ offsets,
                                               int* __restrict__ cursor,
                                               float* __restrict__ out) {
    __shared__ int tmp[NLAB];
    const int t = threadIdx.x;
    int v = 0;
    if (t < NLAB) { v = hist[t]; tmp[t] = v; }
    __syncthreads();
    for (int off = 1; off < NLAB; off <<= 1) {
        int add = 0;
        if (t < NLAB && t >= off) add = tmp[t - off];
        __syncthreads();
        if (t < NLAB) tmp[t] += add;
        __syncthreads();
    }
    if (t < NLAB) {
        int excl = tmp[t] - v;
        offsets[t] = excl;
        cursor[t]  = excl;
    }
    if (t == 0) { offsets[NLAB] = NROWS; out[0] = 0.0f; }
}

// ---------- R2-verified: scatter row indices into label-sorted order ----------
__global__ __launch_bounds__(256) void k_scatter(const int* __restrict__ labels,
                                                 int* __restrict__ cursor,
                                                 int* __restrict__ order) {
    for (int i = blockIdx.x * 256 + threadIdx.x; i < NROWS; i += gridDim.x * 256) {
        const int l = labels[i];
        const int pos = atomicAdd(&cursor[l], 1);
        order[pos] = i;
    }
}

// ---------- x -> gated z' rows, coalesced global write (no accumulator) ----
// 512-thr blocks (8 waves), XT=32, LDS 24KB, <=128 VGPR -> 2 blocks/CU.
// phases: {pack+PREF+sA} bar1 {MFMA + zst + gate} bar2 {coalesced z-out}.
__global__ __launch_bounds__(512, 4) void k_xz(
    const float* __restrict__ x,
    const float* __restrict__ w1, const float* __restrict__ b1,
    const float* __restrict__ w2, unsigned* __restrict__ Zg)
{
    __shared__ __align__(16) unsigned short sA[XT * ASTRIDE];   // 16,896 B
    __shared__ __align__(16) float zst[XT][52];                 //  6,656 B

    const int tid = threadIdx.x, lane = tid & 63, wib = tid >> 6;
    const int bid = blockIdx.x;
    const int mh = wib >> 2, jt = wib & 3;

    frag_ab bfr[8];
    {
        const int n = 16 * jt + (lane & 15);
        #pragma unroll
        for (int s = 0; s < 8; ++s) {
            const int k0 = 32 * s + (lane >> 4) * 8;
            #pragma unroll
            for (int i = 0; i < 8; ++i) {
                const int kk = k0 + i;
                float v = 0.f;
                if (n < YDIM)       v = w2[kk * YDIM + n];
                else if (n == YDIM) v = w1[kk];
                bfr[s][i] = (short)f2b(v);
            }
        }
    }
    const float b1v = b1[0];
    const bool gate_lane = (jt == 3) && ((lane & 15) == 2);   // zc == 50

    auto PREF = [&](int t, float4* r) {
        #pragma unroll
        for (int k = 0; k < 4; ++k) {
            const int rg = t * XT + 4 * wib + k;   // NROWS % XT == 0: always valid
            r[k] = (t < NTX)
                 ? reinterpret_cast<const float4*>(x)[(size_t)rg * 64 + lane]
                 : make_float4(0.f, 0.f, 0.f, 0.f);
        }
    };

    auto process = [&](int t, int pft, float4* r) {
        // phase 0: pack current rows, prefetch next set, stage A
        uint2 pk[4];
        #pragma unroll
        for (int k = 0; k < 4; ++k) {
            pk[k].x = cvt_pk_bf16(r[k].x, r[k].y);
            pk[k].y = cvt_pk_bf16(r[k].z, r[k].w);
        }
        PREF(pft, r);
        const int row = 4 * wib;
        #pragma unroll
        for (int k = 0; k < 4; ++k)
            *reinterpret_cast<uint2*>(&sA[(row + k) * ASTRIDE + lane * 4]) = pk[k];
        bar_lds();                     // sA ready

        // phase 1: MFMA; stage z'-cols 0..49; gate -> col 51
        frag_cd c = {0.f, 0.f, 0.f, 0.f};
        #pragma unroll
        for (int s = 0; s < 8; ++s) {
            frag_ab a = *reinterpret_cast<const frag_ab*>(
                &sA[(16 * mh + (lane & 15)) * ASTRIDE + 32 * s + (lane >> 4) * 8]);
            c = __builtin_amdgcn_mfma_f32_16x16x32_bf16(a, bfr[s], c, 0, 0, 0);
        }
        const int zr = 16 * mh + (lane >> 4) * 4;
        const int zc = 16 * jt + (lane & 15);
        if (zc < YDIM) {
            zst[zr + 0][zc] = c[0]; zst[zr + 1][zc] = c[1];
            zst[zr + 2][zc] = c[2]; zst[zr + 3][zc] = c[3];
        } else if (gate_lane) {
            #pragma unroll
            for (int k = 0; k < 4; ++k)
                zst[zr + k][51] = 1.0f / (1.0f + __expf(-(c[k] + b1v)));
        }
        bar_lds();                     // zst ready

        // phase 2: coalesced gated z write: 32 rows x 25 u32 (128 B stride)
        {
            const int s = tid & 31;
            const int r2 = tid >> 5;   // 0..15
            #pragma unroll
            for (int p = 0; p < 2; ++p) {
                const int rr = r2 + 16 * p;
                if (s < 25) {
                    const float g = zst[rr][51];
                    const float2 zv =
                        *reinterpret_cast<const float2*>(&zst[rr][2 * s]);
                    Zg[((size_t)t * XT + rr) * ZSTR + s] =
                        cvt_pk_bf16(g * zv.x, g * zv.y);
                }
            }
        }
        // zst reads drain at next tile's bar1 before phase-1 rewrite
    };

    float4 rA[4], rB[4];
    PREF(bid, rA);
    PREF(bid + XBLK, rB);
    for (int t = bid; t < NTX; t += 2 * XBLK) {
        process(t, t + 2 * XBLK, rA);
        if (t + XBLK < NTX) process(t + XBLK, t + 3 * XBLK, rB);
    }
}

// ---------- per-label gather-reduce (z L3-hot + y) + double softmax + loss --
__global__ __launch_bounds__(256) void k_reduce(
    const unsigned* __restrict__ Zg, const float* __restrict__ y,
    const int* __restrict__ order, const int* __restrict__ offsets,
    const float* __restrict__ b2, float* __restrict__ out)
{
    const int l = blockIdx.x;
    const int tid = threadIdx.x, lane = tid & 63, wib = tid >> 6;
    const int half = lane >> 5, li = lane & 31;

    const int start = offsets[l];
    const int end   = offsets[l + 1];
    const int cnt   = end - start;

    float zx = 0.f, zy = 0.f, yx = 0.f, yy = 0.f;
    const bool act25 = li < 25;

    int pos = start + 2 * wib + half;
    int idx_next = (pos < end) ? order[pos] : 0;
    for (; pos < end; pos += 8) {
        const int idx = idx_next;
        const int np = pos + 8;
        if (np < end) idx_next = order[np];
        if (act25) {
            const unsigned zp = Zg[(size_t)idx * ZSTR + li];
            const float2 yv = *reinterpret_cast<const float2*>(
                &y[(size_t)idx * YDIM + 2 * li]);
            zx += b2f((unsigned short)(zp & 0xffffu));
            zy += b2f((unsigned short)(zp >> 16));
            yx += yv.x;
            yy += yv.y;
        }
    }
    // combine halves (same cols, disjoint rows)
    zx += __shfl_xor(zx, 32); zy += __shfl_xor(zy, 32);
    yx += __shfl_xor(yx, 32); yy += __shfl_xor(yy, 32);

    __shared__ float sz[4][25][2], sy[4][25][2];
    if (half == 0 && act25) {
        sz[wib][li][0] = zx; sz[wib][li][1] = zy;
        sy[wib][li][0] = yx; sy[wib][li][1] = yy;
    }
    __syncthreads();

    __shared__ float zsum[52], ysum[52];
    if (wib == 0 && lane < 25) {
        float a0 = 0.f, a1 = 0.f, b0 = 0.f, b1s = 0.f;
        #pragma unroll
        for (int w = 0; w < 4; ++w) {
            a0 += sz[w][lane][0]; a1 += sz[w][lane][1];
            b0 += sy[w][lane][0]; b1s += sy[w][lane][1];
        }
        zsum[2 * lane] = a0; zsum[2 * lane + 1] = a1;
        ysum[2 * lane] = b0; ysum[2 * lane + 1] = b1s;
    }
    __syncthreads();
    if (wib != 0) return;

    const float denom = fmaxf((float)cnt, 1.0f);
    const bool act = lane < YDIM;
    const float NEG = -3.402823466e38f;
    float logit = act ? (zsum[lane] / denom + b2[lane]) : NEG;
    const float ymean = act ? (ysum[lane] / denom) : 0.f;

    float m = logit;
    #pragma unroll
    for (int o = 32; o > 0; o >>= 1) m = fmaxf(m, __shfl_xor(m, o));
    float e = act ? __expf(logit - m) : 0.f;
    float s = e;
    #pragma unroll
    for (int o = 32; o > 0; o >>= 1) s += __shfl_xor(s, o);
    const float p = e / s;                 // prediction

    float pm = act ? p : NEG;              // faithful double softmax
    float m2 = pm;
    #pragma unroll
    for (int o = 32; o > 0; o >>= 1) m2 = fmaxf(m2, __shfl_xor(m2, o));
    float e2 = act ? __expf(p - m2) : 0.f;
    float s2 = e2;
    #pragma unroll
    for (int o = 32; o > 0; o >>= 1) s2 += __shfl_xor(s2, o);
    const float logp = p - m2 - __logf(s2);

    float contrib = act ? ymean * logp : 0.f;
    #pragma unroll
    for (int o = 32; o > 0; o >>= 1) contrib += __shfl_xor(contrib, o);
    if (lane == 0) atomicAdd(out, -contrib / (float)NLAB);
}

extern "C" void kernel_launch(void* const* d_in, const int* in_sizes, int n_in,
                              void* d_out, int out_size, void* d_ws, size_t ws_size,
                              hipStream_t stream) {
    const float* x      = (const float*)d_in[0];
    const int*   labels = (const int*)  d_in[1];
    const float* y      = (const float*)d_in[2];
    const float* w1     = (const float*)d_in[3];
    const float* b1     = (const float*)d_in[4];
    const float* w2     = (const float*)d_in[5];
    const float* b2     = (const float*)d_in[6];
    float* out = (float*)d_out;

    // ws: hist[1024] | offsets[1024+1] | cursor[1024] | order[500000]
    //     | Zg[500000*32 u32] (64 MB, at 4 MB offset)
    char* w = (char*)d_ws;
    int* hist    = (int*)w;
    int* offsets = (int*)(w + 4096);
    int* cursor  = (int*)(w + 12288);
    int* order   = (int*)(w + 16384);
    unsigned* Zg = (unsigned*)(w + (4u << 20));

    hipMemsetAsync(hist, 0, NLAB * sizeof(int), stream);
    k_hist<<<256, 256, 0, stream>>>(labels, hist);
    k_scan<<<1, 1024, 0, stream>>>(hist, offsets, cursor, out);
    k_scatter<<<512, 256, 0, stream>>>(labels, cursor, order);
    k_xz<<<XBLK, 512, 0, stream>>>(x, w1, b1, w2, Zg);
    k_reduce<<<NLAB, 256, 0, stream>>>(Zg, y, order, offsets, b2, out);
}

// Round 21
// 196.116 us; speedup vs baseline: 1.5210x; 1.5210x over previous
//
#include <hip/hip_runtime.h>
#include <math.h>

#define NROWS 500000
#define DIM 256
#define YDIM 50
#define NLAB 1000

#define XT 64
#define NTX ((NROWS + XT - 1) / XT)      // 7813 (last tile: 32 valid rows)
#define XBLOCKS 256
#define ASTRIDE 264                      // bf16 elems per A-tile row (padded)
#define ZC 51                            // z' cols: 50 proj + 1 gate-dot

#define YT 128
#define NTY ((NROWS + YT - 1) / YT)      // 3907
#define YBLOCKS 256

typedef __attribute__((ext_vector_type(8))) short frag_ab;
typedef __attribute__((ext_vector_type(4))) float frag_cd;

__device__ __forceinline__ float b2f(unsigned short u) {
    return __uint_as_float(((unsigned)u) << 16);
}
__device__ __forceinline__ unsigned short f2b(float f) {   // RNE f32->bf16
    unsigned u = __float_as_uint(f);
    return (unsigned short)((u + 0x7fffu + ((u >> 16) & 1u)) >> 16);
}
// LDS-only barrier: does NOT drain vmcnt -> global prefetches stay in flight.
__device__ __forceinline__ void bar_lds() {
    asm volatile("s_waitcnt lgkmcnt(0)\n\ts_barrier" ::: "memory");
}

// ============ x stream: z' = x @ [w2|w1]; gate applied post-MFMA ============
// 2 barriers/tile: bar1 = sA+slab ready, bar2 = zst ready.
// Wave w owns labels (lbl&15)==w -> accz RMW race-free, scatter needs no
// trailing barrier (zst/slab reuse protected by next tile's bar1).
__global__ __launch_bounds__(1024) void k_xstream(
    const float* __restrict__ x, const int* __restrict__ labels,
    const float* __restrict__ w1, const float* __restrict__ b1,
    const float* __restrict__ w2, unsigned short* __restrict__ zpart,
    float* __restrict__ out)
{
    __shared__ __align__(16) unsigned short sA[XT * ASTRIDE];   // 33,792 B
    __shared__ __align__(16) float zst[XT][52];                 // 13,312 B
    __shared__ __align__(16) unsigned short accz[NLAB * YDIM];  // 100,000 B
    __shared__ int slab[2][XT];                                 //    512 B

    const int tid = threadIdx.x, lane = tid & 63, wib = tid >> 6;
    const int bid = blockIdx.x;
    const int mh = wib >> 2, jt = wib & 3;

    if (bid == 0 && tid == 0) out[0] = 0.0f;
    for (int k = tid; k < NLAB * YDIM / 2; k += 1024)
        reinterpret_cast<unsigned*>(accz)[k] = 0u;

    // B fragments: W' columns = [w2 cols 0..49 | w1 as col 50 | zeros]
    frag_ab bfr[8];
    {
        const int n = 16 * jt + (lane & 15);
        #pragma unroll
        for (int s = 0; s < 8; ++s) {
            const int k0 = 32 * s + (lane >> 4) * 8;
            #pragma unroll
            for (int i = 0; i < 8; ++i) {
                const int kk = k0 + i;
                float v = 0.f;
                if (n < YDIM)       v = w2[kk * YDIM + n];
                else if (n == YDIM) v = w1[kk];
                bfr[s][i] = (short)f2b(v);
            }
        }
    }
    const float b1v = b1[0];
    __syncthreads();                                  // accz zeroed

    auto PREF = [&](int t, float4* r) {
        #pragma unroll
        for (int k = 0; k < 4; ++k) {
            const int rg = t * XT + 4 * wib + k;
            r[k] = (rg < NROWS)
                 ? reinterpret_cast<const float4*>(x)[(size_t)rg * 64 + lane]
                 : make_float4(0.f, 0.f, 0.f, 0.f);
        }
    };
    auto LLAB = [&](int t) -> int {
        const int rg = t * XT + tid;
        return (tid < XT && rg < NROWS) ? labels[rg] : 0;
    };

    auto process = [&](int pft, float4* r, int& lb, int par) {
        // ---- phase 0: slab, pack x->bf16, refill prefetch, A-write ----
        if (tid < XT) slab[par][tid] = lb;
        uint2 pk[4];
        #pragma unroll
        for (int k = 0; k < 4; ++k) {
            pk[k].x = (unsigned)f2b(r[k].x) | ((unsigned)f2b(r[k].y) << 16);
            pk[k].y = (unsigned)f2b(r[k].z) | ((unsigned)f2b(r[k].w) << 16);
        }
        PREF(pft, r);                  // depth-2: loads stay in flight
        lb = LLAB(pft);                // labels travel with this reg set
        const int row = 4 * wib;
        #pragma unroll
        for (int k = 0; k < 4; ++k)
            *reinterpret_cast<uint2*>(&sA[(row + k) * ASTRIDE + lane * 4]) = pk[k];
        bar_lds();                     // bar1: sA + slab[par] ready

        // ---- phase 1: MFMA (gate col rides along), stage z'-tile ----
        frag_cd c = {0.f, 0.f, 0.f, 0.f};
        #pragma unroll
        for (int s = 0; s < 8; ++s) {
            frag_ab a = *reinterpret_cast<const frag_ab*>(
                &sA[(16 * mh + (lane & 15)) * ASTRIDE + 32 * s + (lane >> 4) * 8]);
            c = __builtin_amdgcn_mfma_f32_16x16x32_bf16(a, bfr[s], c, 0, 0, 0);
        }
        const int zr = 16 * mh + (lane >> 4) * 4;
        const int zc = 16 * jt + (lane & 15);
        if (zc < ZC) {
            zst[zr + 0][zc] = c[0]; zst[zr + 1][zc] = c[1];
            zst[zr + 2][zc] = c[2]; zst[zr + 3][zc] = c[3];
        }
        bar_lds();                     // bar2: zst ready

        // ---- phase 2: gated, label-partitioned scatter ----
        {
            const int lbl_lane = slab[par][lane];
            unsigned long long mask = __ballot((lbl_lane & 15) == wib);
            while (mask) {
                const int r2 = __builtin_ctzll(mask);
                mask &= mask - 1;
                const int lbv = __shfl(lbl_lane, r2);
                const float d = zst[r2][YDIM];           // broadcast read
                const float g = 1.0f / (1.0f + __expf(-(d + b1v)));
                if (lane < YDIM) {
                    const int a = lbv * YDIM + lane;
                    accz[a] = f2b(b2f(accz[a]) + g * zst[r2][lane]);
                }
            }
        }
    };

    float4 rA[4], rB[4];
    PREF(bid, rA);
    PREF(bid + XBLOCKS, rB);
    int lbA = LLAB(bid), lbB = LLAB(bid + XBLOCKS);
    int par = 0;
    for (int t = bid; t < NTX; t += 2 * XBLOCKS) {
        process(t + 2 * XBLOCKS, rA, lbA, par); par ^= 1;
        if (t + XBLOCKS < NTX) {
            process(t + 3 * XBLOCKS, rB, lbB, par); par ^= 1;
        }
    }
    __syncthreads();
    unsigned short* zp = zpart + (size_t)bid * (NLAB * YDIM);
    for (int k = tid; k < NLAB * YDIM; k += 1024) zp[k] = accz[k];
}

// ============ y stream: 1 barrier/tile, depth-2 prefetch, + counts ============
__global__ __launch_bounds__(1024) void k_ystream(
    const float* __restrict__ y, const int* __restrict__ labels,
    unsigned short* __restrict__ ypart, int* __restrict__ gcnt)
{
    __shared__ __align__(16) unsigned short accy[NLAB * YDIM];  // 100,000 B
    __shared__ __align__(16) float yst[2][YT * YDIM];           //  51,200 B
    __shared__ int slab[2][YT];                                 //   1,024 B
    __shared__ int cnt[NLAB];                                   //   4,000 B

    const int tid = threadIdx.x, lane = tid & 63, wib = tid >> 6;
    const int bid = blockIdx.x;

    for (int k = tid; k < NLAB * YDIM / 2; k += 1024)
        reinterpret_cast<unsigned*>(accy)[k] = 0u;
    for (int k = tid; k < NLAB; k += 1024) cnt[k] = 0;
    __syncthreads();

    auto PREFY = [&](int t, float* v, int& myl) {
        const size_t base = (size_t)t * YT * YDIM;
        const int n = (t < NTY) ? (min(YT, NROWS - t * YT) * YDIM) : 0;
        #pragma unroll
        for (int i = 0; i < 7; ++i) {
            const int k = tid + i * 1024;
            v[i] = (k < n) ? y[base + k] : 0.f;
        }
        const int rg = t * YT + tid;
        myl = (tid < YT && t < NTY && rg < NROWS) ? labels[rg] : -1;
    };

    auto process = [&](int pft, float* v, int& myl, int par) {
        #pragma unroll
        for (int i = 0; i < 7; ++i) {
            const int k = tid + i * 1024;
            if (k < YT * YDIM) yst[par][k] = v[i];
        }
        if (tid < YT) {
            const bool valid = (myl >= 0);
            slab[par][tid] = valid ? myl : 0;
            if (valid) atomicAdd(&cnt[myl], 1);
        }
        PREFY(pft, v, myl);            // depth-2: next-next tile in flight
        bar_lds();                     // yst[par] + slab[par] ready

        {
            const int l0 = slab[par][lane];
            const int l1 = slab[par][64 + lane];
            unsigned long long m0 = __ballot((l0 & 15) == wib);
            unsigned long long m1 = __ballot((l1 & 15) == wib);
            while (m0) {
                const int r = __builtin_ctzll(m0); m0 &= m0 - 1;
                const int lb = __shfl(l0, r);
                if (lane < YDIM) {
                    const int a = lb * YDIM + lane;
                    accy[a] = f2b(b2f(accy[a]) + yst[par][r * YDIM + lane]);
                }
            }
            while (m1) {
                const int r = __builtin_ctzll(m1); m1 &= m1 - 1;
                const int lb = __shfl(l1, r);
                if (lane < YDIM) {
                    const int a = lb * YDIM + lane;
                    accy[a] = f2b(b2f(accy[a]) + yst[par][(64 + r) * YDIM + lane]);
                }
            }
        }
        // next tile writes yst[par^1]; yst[par] rewrite is >=1 barrier away.
    };

    float vA[7], vB[7];
    int mA, mB;
    PREFY(bid, vA, mA);
    PREFY(bid + YBLOCKS, vB, mB);
    int par = 0;
    for (int t = bid; t < NTY; t += 2 * YBLOCKS) {
        process(t + 2 * YBLOCKS, vA, mA, par); par ^= 1;
        if (t + YBLOCKS < NTY) {
            process(t + 3 * YBLOCKS, vB, mB, par); par ^= 1;
        }
    }
    __syncthreads();
    unsigned short* yp = ypart + (size_t)bid * (NLAB * YDIM);
    for (int k = tid; k < NLAB * YDIM; k += 1024) yp[k] = accy[k];
    for (int k = tid; k < NLAB; k += 1024)
        if (cnt[k]) atomicAdd(&gcnt[k], cnt[k]);
}

// ============ finalize: coalesced partial-reduce + double softmax + loss ===
__global__ __launch_bounds__(256) void k_finalize(
    const unsigned short* __restrict__ zpart,
    const unsigned short* __restrict__ ypart,
    const int* __restrict__ gcnt,
    const float* __restrict__ b2, float* __restrict__ out)
{
    const int tid = threadIdx.x, lane = tid & 63, grp = tid >> 6;
    const int k0 = blockIdx.x * 200;

    float zs = 0.f, ys = 0.f;
    if (tid < 200) {
        const size_t idx = (size_t)k0 + tid;
        #pragma unroll 4
        for (int p = 0; p < XBLOCKS; ++p) {
            zs += b2f(zpart[(size_t)p * (NLAB * YDIM) + idx]);
            ys += b2f(ypart[(size_t)p * (NLAB * YDIM) + idx]);
        }
    }
    __shared__ float zl[200], yl[200];
    if (tid < 200) { zl[tid] = zs; yl[tid] = ys; }
    __syncthreads();

    const int l = blockIdx.x * 4 + grp;
    const bool act = lane < YDIM;
    const float zv = act ? zl[grp * 50 + lane] : 0.f;
    const float yv = act ? yl[grp * 50 + lane] : 0.f;

    const float denom = fmaxf((float)gcnt[l], 1.0f);
    const float NEG = -3.402823466e38f;
    float logit = act ? (zv / denom + b2[lane]) : NEG;
    const float ymean = act ? (yv / denom) : 0.f;

    float m = logit;
    #pragma unroll
    for (int o = 32; o > 0; o >>= 1) m = fmaxf(m, __shfl_xor(m, o));
    float e = act ? __expf(logit - m) : 0.f;
    float s = e;
    #pragma unroll
    for (int o = 32; o > 0; o >>= 1) s += __shfl_xor(s, o);
    const float p = e / s;                 // prediction

    float pm = act ? p : NEG;              // faithful double softmax
    float m2 = pm;
    #pragma unroll
    for (int o = 32; o > 0; o >>= 1) m2 = fmaxf(m2, __shfl_xor(m2, o));
    float e2 = act ? __expf(p - m2) : 0.f;
    float s2 = e2;
    #pragma unroll
    for (int o = 32; o > 0; o >>= 1) s2 += __shfl_xor(s2, o);
    const float logp = p - m2 - __logf(s2);

    float contrib = act ? ymean * logp : 0.f;
    #pragma unroll
    for (int o = 32; o > 0; o >>= 1) contrib += __shfl_xor(contrib, o);
    if (lane == 0) atomicAdd(out, -contrib / (float)NLAB);
}

extern "C" void kernel_launch(void* const* d_in, const int* in_sizes, int n_in,
                              void* d_out, int out_size, void* d_ws, size_t ws_size,
                              hipStream_t stream) {
    const float* x      = (const float*)d_in[0];
    const int*   labels = (const int*)  d_in[1];
    const float* y      = (const float*)d_in[2];
    const float* w1     = (const float*)d_in[3];
    const float* b1     = (const float*)d_in[4];
    const float* w2     = (const float*)d_in[5];
    const float* b2     = (const float*)d_in[6];
    float* out = (float*)d_out;

    // ws: gcnt[1024] ints | zpart[256][50000] bf16 | ypart[256][50000] bf16
    int* gcnt = (int*)d_ws;
    unsigned short* zpart = (unsigned short*)((char*)d_ws + 4096);
    unsigned short* ypart = (unsigned short*)((char*)d_ws + 4096 +
                             (size_t)XBLOCKS * NLAB * YDIM * 2);

    hipMemsetAsync(gcnt, 0, NLAB * sizeof(int), stream);
    k_xstream<<<XBLOCKS, 1024, 0, stream>>>(x, labels, w1, b1, w2, zpart, out);
    k_ystream<<<YBLOCKS, 1024, 0, stream>>>(y, labels, ypart, gcnt);
    k_finalize<<<250, 256, 0, stream>>>(zpart, ypart, gcnt, b2, out);
}